// Round 6
// baseline (959.673 us; speedup 1.0000x reference)
//
#include <hip/hip_runtime.h>
#include <hip/hip_bf16.h>
#include <cstdint>
#include <cstddef>

constexpr int BROWS   = 16384;
constexpr int OBJ_FEAT = 1024;
constexpr int PPF_DIM  = 64;
constexpr int HIDDEN   = 512;
constexpr int OBJ_NUM  = 1001;
constexpr int PRED_NUM = 132;
constexpr int OBJ_PAD  = 1024;
constexpr int PRED_PAD = 256;
constexpr int PF_K     = HIDDEN + PPF_DIM;  // 576

typedef __attribute__((ext_vector_type(8))) short bf16x8;
typedef __attribute__((ext_vector_type(4))) float f32x4;

static __device__ __forceinline__ unsigned short f2bf(float f) {
  unsigned int u = __float_as_uint(f);
  u += 0x7fffu + ((u >> 16) & 1u);
  return (unsigned short)(u >> 16);
}

// All 5 weight transposes in one dispatch. W [K,N] fp32 -> Wt [Npad,K] bf16,
// zero-padded for n >= N. Branch on blockIdx.z (block-uniform).
__global__ void cast_w_all(const float* __restrict__ W0, const float* __restrict__ W1,
                           const float* __restrict__ W2, const float* __restrict__ W3,
                           const float* __restrict__ W4,
                           unsigned short* __restrict__ T0, unsigned short* __restrict__ T1,
                           unsigned short* __restrict__ T2, unsigned short* __restrict__ T3,
                           unsigned short* __restrict__ T4) {
  const int z = blockIdx.z;
  const float* W; unsigned short* T; int K, N, Npad;
  if      (z == 0) { W = W0; T = T0; K = 1024; N = 512;  Npad = 512;  }
  else if (z == 1) { W = W1; T = T1; K = 512;  N = 1001; Npad = 1024; }
  else if (z == 2) { W = W2; T = T2; K = 1024; N = 512;  Npad = 512;  }
  else if (z == 3) { W = W3; T = T3; K = 576;  N = 512;  Npad = 512;  }
  else             { W = W4; T = T4; K = 512;  N = 132;  Npad = 256;  }
  int n = blockIdx.y;
  int k = blockIdx.x * 256 + threadIdx.x;
  if (n >= Npad || k >= K) return;
  float v = (n < N) ? W[(size_t)k * N + n] : 0.0f;
  T[(size_t)n * K + k] = f2bf(v);
}

// ---------------- fused GEMM ----------------
// C[M,N] = A[M,K] * Bt[N,K]^T, 128x128 tile, BK=64 (2 k-slices of 32),
// 4 waves (2x2), 4x4 MFMA 16x16x32 per wave.
// LDS layout: [2 slices][128 rows][32 cols] per operand — per-slice geometry
// identical to the HW-verified BK=32 kernel (same bank behavior), and the
// global_load_lds destination stays exactly lane-linear (slot = ls*16B);
// only the per-lane GLOBAL source address encodes the (slice,row,col) map.
// Halves the per-K-step barrier+vmcnt-drain count vs BK=32.
// bf16 region  k <  K1 : A1 (ld ldA1), staged via global_load_lds width-16.
// fp32 region  k >= K1 (FPA=1 only): A row-split 3-way
//   (m0 < M1f -> Af0 ; m0 < Msplit -> Af1 rebased ; else Af2 rebased, ld ldAf),
//   float4-prefetched into regs during the MFMA phase, converted, ds_written.
// M-split: m0 >= Msplit also switches B/bias to {Btb, biasb}.
// MODE 0: outB bf16 = relu(acc + bias[n])
// MODE 1: outF fp32 = acc
// MODE 2: outF fp32 = acc + so2p[gts[m]*OBJ_NUM+gto[m]][n] * exp(factor)
template <int MODE, int FPA>
__global__ __launch_bounds__(256)
void gemm_fused(const unsigned short* __restrict__ A1, int ldA1, int K1,
                const float* __restrict__ Af0, const float* __restrict__ Af1,
                const float* __restrict__ Af2, int M1f, int ldAf,
                const unsigned short* __restrict__ Bt, int K,
                int Msplit,
                const unsigned short* __restrict__ Btb,
                const float* __restrict__ biasb,
                float* __restrict__ outF, unsigned short* __restrict__ outB,
                int ldout, int Nreal,
                const float* __restrict__ bias,
                const int* __restrict__ gts, const int* __restrict__ gto,
                const float* __restrict__ so2p, const float* __restrict__ factor) {
  __shared__ unsigned short sA[2 * 128 * 32];
  __shared__ unsigned short sB[2 * 128 * 32];

  const int tid  = threadIdx.x;
  const int lane = tid & 63;
  const int wave = tid >> 6;
  const int wm   = wave >> 1;
  const int wn   = wave & 1;
  const int quad = lane >> 4;
  const int r16  = lane & 15;

  // XCD-aware bijective swizzle (all grids have nwg % 8 == 0): the n-tile
  // blocks sharing one A-tile become id-consecutive -> same XCD L2.
  const int nwg = gridDim.x * gridDim.y;
  const int id  = blockIdx.y * gridDim.x + blockIdx.x;
  const int cpx = nwg >> 3;
  const int t   = (id & 7) * cpx + (id >> 3);
  const int m0  = (t / gridDim.x) * 128;
  const int n0  = (t % gridDim.x) * 128;

  const unsigned short* Bbase = Bt;
  const float* bias_p = bias;
  if (m0 >= Msplit) { Bbase = Btb; bias_p = biasb; }

  // block-uniform fp32 A base (128-row tiles never straddle M1f/Msplit:
  // all boundaries are multiples of 128)
  const float* afb = nullptr;
  if constexpr (FPA) {
    if (m0 >= Msplit)    afb = Af2 + (size_t)(m0 - Msplit) * ldAf;
    else if (m0 < M1f)   afb = Af0 + (size_t)m0 * ldAf;
    else                 afb = Af1 + (size_t)(m0 - M1f) * ldAf;
  }

  float4 pa[8];
  auto loadA = [&](int k0) {
    const int kf = k0 - K1;
#pragma unroll
    for (int j = 0; j < 8; ++j) {
      int ch = tid + j * 256, row = ch >> 4, c4 = (ch & 15) * 4;  // fp32 col in [0,64)
      pa[j] = *reinterpret_cast<const float4*>(afb + (size_t)row * ldAf + kf + c4);
    }
  };
  if constexpr (FPA) {
    if (K1 == 0) loadA(0);  // K1>0 cases prefetch at iter K1-64
  }

  f32x4 acc[4][4] = {};

  for (int k0 = 0; k0 < K; k0 += 64) {
    __syncthreads();  // previous iter's LDS reads done
    if (!FPA || k0 < K1) {
      // LDS slot ls -> (slice s=ls>>9, row=(ls>>2)&127, c=ls&3); dst = ls*16B
      // (lane-linear); global col = s*32 + c*8.
#pragma unroll
      for (int j = 0; j < 4; ++j) {
        int ls = tid + j * 256;
        int s = ls >> 9, row = (ls >> 2) & 127, c = ls & 3;
        const unsigned short* ga =
            A1 + (size_t)(m0 + row) * ldA1 + k0 + s * 32 + c * 8;
        __builtin_amdgcn_global_load_lds(
            (const __attribute__((address_space(1))) void*)ga,
            (__attribute__((address_space(3))) void*)(sA + ls * 8), 16, 0, 0);
      }
    } else {
      // consume prefetched fp32 tile: convert + stage into split-slice layout
#pragma unroll
      for (int j = 0; j < 8; ++j) {
        int ch = tid + j * 256, row = ch >> 4, c4 = (ch & 15) * 4;  // col in [0,64)
        ushort4 o;
        o.x = f2bf(pa[j].x); o.y = f2bf(pa[j].y);
        o.z = f2bf(pa[j].z); o.w = f2bf(pa[j].w);
        int s = c4 >> 5, cw = c4 & 31;
        *reinterpret_cast<ushort4*>(sA + s * 4096 + row * 32 + cw) = o;
      }
    }
#pragma unroll
    for (int j = 0; j < 4; ++j) {
      int ls = tid + j * 256;
      int s = ls >> 9, row = (ls >> 2) & 127, c = ls & 3;
      const unsigned short* gb =
          Bbase + (size_t)(n0 + row) * K + k0 + s * 32 + c * 8;
      __builtin_amdgcn_global_load_lds(
          (const __attribute__((address_space(1))) void*)gb,
          (__attribute__((address_space(3))) void*)(sB + ls * 8), 16, 0, 0);
    }
    __syncthreads();  // staging visible (compiler drains vmcnt before barrier)

    // prefetch next fp32 A tile into regs — latency hides behind MFMA phase
    if constexpr (FPA) {
      int kn = k0 + 64;
      if (kn >= K1 && kn < K) loadA(kn);
    }

#pragma unroll
    for (int s = 0; s < 2; ++s) {
      bf16x8 af[4], bfr[4];
#pragma unroll
      for (int i = 0; i < 4; ++i)
        af[i] = *reinterpret_cast<const bf16x8*>(
            sA + s * 4096 + (wm * 64 + i * 16 + r16) * 32 + quad * 8);
#pragma unroll
      for (int j = 0; j < 4; ++j)
        bfr[j] = *reinterpret_cast<const bf16x8*>(
            sB + s * 4096 + (wn * 64 + j * 16 + r16) * 32 + quad * 8);
#pragma unroll
      for (int i = 0; i < 4; ++i)
#pragma unroll
        for (int j = 0; j < 4; ++j)
          acc[i][j] = __builtin_amdgcn_mfma_f32_16x16x32_bf16(af[i], bfr[j], acc[i][j], 0, 0, 0);
    }
  }

  float ef = 0.0f;
  if (MODE == 2) ef = expf(factor[0]);

#pragma unroll
  for (int i = 0; i < 4; ++i) {
    int mbase = m0 + wm * 64 + i * 16 + quad * 4;
#pragma unroll
    for (int reg = 0; reg < 4; ++reg) {
      int m = mbase + reg;
      // MODE 2: hoist the dependent gather chain (gts/gto -> rowidx) per m.
      const float* so_row = nullptr;
      if (MODE == 2) {
        long rowidx = (long)gts[m] * OBJ_NUM + gto[m];
        so_row = so2p + rowidx * PRED_NUM;
      }
#pragma unroll
      for (int j = 0; j < 4; ++j) {
        int n = n0 + wn * 64 + j * 16 + r16;
        if (n < Nreal) {
          float v = acc[i][j][reg];
          if (MODE == 0) {
            v = fmaxf(v + bias_p[n], 0.0f);
            outB[(size_t)m * ldout + n] = f2bf(v);
          } else if (MODE == 1) {
            outF[(size_t)m * ldout + n] = v;
          } else {
            v += so_row[n] * ef;
            outF[(size_t)m * ldout + n] = v;
          }
        }
      }
    }
  }
}

// ---------------- launch ----------------

extern "C" void kernel_launch(void* const* d_in, const int* in_sizes, int n_in,
                              void* d_out, int out_size, void* d_ws, size_t ws_size,
                              hipStream_t stream) {
  const float* inp_sf  = (const float*)d_in[0];
  const float* inp_of  = (const float*)d_in[1];
  const float* inp_ppf = (const float*)d_in[2];
  const float* inp_pvf = (const float*)d_in[3];
  const int*   gt_s    = (const int*)d_in[4];
  const int*   gt_o    = (const int*)d_in[5];
  const float* W_obj1  = (const float*)d_in[6];
  const float* b_obj1  = (const float*)d_in[7];
  const float* W_obj2  = (const float*)d_in[8];
  const float* W_pvf   = (const float*)d_in[9];
  const float* b_pvf   = (const float*)d_in[10];
  const float* W_pf    = (const float*)d_in[11];
  const float* b_pf    = (const float*)d_in[12];
  const float* W_pred  = (const float*)d_in[13];
  const float* so2p    = (const float*)d_in[14];
  const float* so2p_f  = (const float*)d_in[15];

  float* out_s = (float*)d_out;                         // [16384,1001] (+ out_o right after)
  float* out_p = out_s + 2 * (size_t)BROWS * OBJ_NUM;   // [16384,132]

  char* ws = (char*)d_ws;
  unsigned short* H_buf = (unsigned short*)ws; ws += (size_t)3 * BROWS * HIDDEN * 2;  // 48 MB: s|o|pvf hidden
  unsigned short* H2    = (unsigned short*)ws; ws += (size_t)BROWS * HIDDEN * 2;      // 16 MB
  unsigned short* Wt_obj1 = (unsigned short*)ws; ws += (size_t)HIDDEN * OBJ_FEAT * 2;
  unsigned short* Wt_obj2 = (unsigned short*)ws; ws += (size_t)OBJ_PAD * HIDDEN * 2;
  unsigned short* Wt_pvf  = (unsigned short*)ws; ws += (size_t)HIDDEN * OBJ_FEAT * 2;
  unsigned short* Wt_pf   = (unsigned short*)ws; ws += (size_t)HIDDEN * PF_K * 2;
  unsigned short* Wt_pred = (unsigned short*)ws; ws += (size_t)PRED_PAD * HIDDEN * 2;

  // 1) weight casts
  cast_w_all<<<dim3(4, 1024, 5), 256, 0, stream>>>(
      W_obj1, W_obj2, W_pvf, W_pf, W_pred,
      Wt_obj1, Wt_obj2, Wt_pvf, Wt_pf, Wt_pred);

  // 2) merged hidden layer: rows [0,16384)=sf, [16384,32768)=of  x W_obj1+b_obj1;
  //    rows [32768,49152)=pvf x W_pvf + b_pvf  -> H_buf bf16 relu.
  //    A is fp32 direct (reg-staged convert path).
  gemm_fused<0, 1><<<dim3(HIDDEN / 128, 3 * BROWS / 128), 256, 0, stream>>>(
      nullptr, 0, 0,
      inp_sf, inp_of, inp_pvf, BROWS, OBJ_FEAT,
      Wt_obj1, OBJ_FEAT,
      2 * BROWS, Wt_pvf, b_pvf,
      nullptr, H_buf, HIDDEN, HIDDEN, b_obj1,
      nullptr, nullptr, nullptr, nullptr);

  // 3) s+o scores: [32768,512] bf16 x W_obj2 -> out_s|out_o fp32
  gemm_fused<1, 0><<<dim3(OBJ_PAD / 128, 2 * BROWS / 128), 256, 0, stream>>>(
      H_buf, HIDDEN, HIDDEN,
      nullptr, nullptr, nullptr, 0, 0,
      Wt_obj2, HIDDEN,
      1 << 30, nullptr, nullptr,
      out_s, nullptr, OBJ_NUM, OBJ_NUM, nullptr,
      nullptr, nullptr, nullptr, nullptr);

  // 4) pf_emb: A = [pvf_emb bf16 (k<512) | ppf fp32 (k>=512)] x W_pf -> H2 relu
  gemm_fused<0, 1><<<dim3(HIDDEN / 128, BROWS / 128), 256, 0, stream>>>(
      H_buf + (size_t)2 * BROWS * HIDDEN, HIDDEN, HIDDEN,
      inp_ppf, nullptr, nullptr, 1 << 30, PPF_DIM,
      Wt_pf, PF_K,
      1 << 30, nullptr, nullptr,
      nullptr, H2, HIDDEN, HIDDEN, b_pf,
      nullptr, nullptr, nullptr, nullptr);

  // 5) p_score + knowledge gather
  gemm_fused<2, 0><<<dim3(PRED_PAD / 128, BROWS / 128), 256, 0, stream>>>(
      H2, HIDDEN, HIDDEN,
      nullptr, nullptr, nullptr, 0, 0,
      Wt_pred, HIDDEN,
      1 << 30, nullptr, nullptr,
      out_p, nullptr, PRED_NUM, PRED_NUM, nullptr,
      gt_s, gt_o, so2p, so2p_f);

  (void)in_sizes; (void)n_in; (void)out_size; (void)ws_size;
}

// Round 10
// 931.576 us; speedup vs baseline: 1.0302x; 1.0302x over previous
//
#include <hip/hip_runtime.h>
#include <hip/hip_bf16.h>
#include <cstdint>
#include <cstddef>

constexpr int BROWS   = 16384;
constexpr int OBJ_FEAT = 1024;
constexpr int PPF_DIM  = 64;
constexpr int HIDDEN   = 512;
constexpr int OBJ_NUM  = 1001;
constexpr int PRED_NUM = 132;
constexpr int OBJ_PAD  = 1024;
constexpr int PRED_PAD = 256;
constexpr int PF_K     = HIDDEN + PPF_DIM;  // 576

typedef __attribute__((ext_vector_type(8))) short bf16x8;
typedef __attribute__((ext_vector_type(4))) float f32x4;

// f2bf via __float2bfloat16 (RNE, bit-identical to the old manual trick) so
// the compiler can pack pairs into v_cvt_pk_bf16_f32 — the manual bit-math
// was ~4 VALU/element and opaque to packing (m240: scalar casts pack, asm
// doesn't). This is the round's single change vs the 937.6 baseline.
static __device__ __forceinline__ unsigned short f2bf(float f) {
  __hip_bfloat16 h = __float2bfloat16(f);
  return *reinterpret_cast<unsigned short*>(&h);
}

// All 5 weight transposes in one dispatch. W [K,N] fp32 -> Wt [Npad,K] bf16,
// zero-padded for n >= N. Branch on blockIdx.z (block-uniform).
__global__ void cast_w_all(const float* __restrict__ W0, const float* __restrict__ W1,
                           const float* __restrict__ W2, const float* __restrict__ W3,
                           const float* __restrict__ W4,
                           unsigned short* __restrict__ T0, unsigned short* __restrict__ T1,
                           unsigned short* __restrict__ T2, unsigned short* __restrict__ T3,
                           unsigned short* __restrict__ T4) {
  const int z = blockIdx.z;
  const float* W; unsigned short* T; int K, N, Npad;
  if      (z == 0) { W = W0; T = T0; K = 1024; N = 512;  Npad = 512;  }
  else if (z == 1) { W = W1; T = T1; K = 512;  N = 1001; Npad = 1024; }
  else if (z == 2) { W = W2; T = T2; K = 1024; N = 512;  Npad = 512;  }
  else if (z == 3) { W = W3; T = T3; K = 576;  N = 512;  Npad = 512;  }
  else             { W = W4; T = T4; K = 512;  N = 132;  Npad = 256;  }
  int n = blockIdx.y;
  int k = blockIdx.x * 256 + threadIdx.x;
  if (n >= Npad || k >= K) return;
  float v = (n < N) ? W[(size_t)k * N + n] : 0.0f;
  T[(size_t)n * K + k] = f2bf(v);
}

// ---------------- fused GEMM ----------------
// C[M,N] = A[M,K] * Bt[N,K]^T, 128x128 tile, BK=32, 4 waves (2x2), 4x4 MFMA
// 16x16x32 per wave (m97 structure).
// bf16 region  k <  K1 : A1 (ld ldA1), staged via global_load_lds width-16.
// fp32 region  k >= K1 (FPA=1 only): A source is row-split 3-way
//   (m0 < M1f -> Af0 ; m0 < Msplit -> Af1 rebased ; else Af2 rebased, ld ldAf),
//   loaded as float4 into regs (prefetched during the MFMA phase), converted
//   to bf16, ds_write-staged.
// M-split: m0 >= Msplit also switches B/bias to {Btb, biasb}
//   (merges the s/o hidden GEMM with the pvf hidden GEMM in one dispatch).
// MODE 0: outB bf16 = relu(acc + bias[n])
// MODE 1: outF fp32 = acc
// MODE 2: outF fp32 = acc + so2p[gts[m]*OBJ_NUM+gto[m]][n] * exp(factor)
template <int MODE, int FPA>
__global__ __launch_bounds__(256)
void gemm_fused(const unsigned short* __restrict__ A1, int ldA1, int K1,
                const float* __restrict__ Af0, const float* __restrict__ Af1,
                const float* __restrict__ Af2, int M1f, int ldAf,
                const unsigned short* __restrict__ Bt, int K,
                int Msplit,
                const unsigned short* __restrict__ Btb,
                const float* __restrict__ biasb,
                float* __restrict__ outF, unsigned short* __restrict__ outB,
                int ldout, int Nreal,
                const float* __restrict__ bias,
                const int* __restrict__ gts, const int* __restrict__ gto,
                const float* __restrict__ so2p, const float* __restrict__ factor) {
  __shared__ unsigned short sA[128 * 32];
  __shared__ unsigned short sB[128 * 32];

  const int tid  = threadIdx.x;
  const int lane = tid & 63;
  const int wave = tid >> 6;
  const int wm   = wave >> 1;
  const int wn   = wave & 1;
  const int quad = lane >> 4;
  const int r16  = lane & 15;

  // XCD-aware bijective swizzle (all grids have nwg % 8 == 0): hardware
  // dispatch order id%8 = XCD; tile t gives each XCD a contiguous tile
  // range, so the gridDim.x n-blocks sharing an A-panel land on one XCD L2.
  const int nwg = gridDim.x * gridDim.y;
  const int id  = blockIdx.y * gridDim.x + blockIdx.x;
  const int cpx = nwg >> 3;
  const int t   = (id & 7) * cpx + (id >> 3);
  const int m0  = (t / gridDim.x) * 128;
  const int n0  = (t % gridDim.x) * 128;

  const unsigned short* Bbase = Bt;
  const float* bias_p = bias;
  if (m0 >= Msplit) { Bbase = Btb; bias_p = biasb; }

  // block-uniform fp32 A base (128-row tiles never straddle M1f/Msplit:
  // all boundaries are multiples of 128)
  const float* afb = nullptr;
  if constexpr (FPA) {
    if (m0 >= Msplit)    afb = Af2 + (size_t)(m0 - Msplit) * ldAf;
    else if (m0 < M1f)   afb = Af0 + (size_t)m0 * ldAf;
    else                 afb = Af1 + (size_t)(m0 - M1f) * ldAf;
  }

  float4 pa[4];
  auto loadA = [&](int k0) {
    const int kf = k0 - K1;
#pragma unroll
    for (int j = 0; j < 4; ++j) {
      int ch = tid + j * 256, row = ch >> 3, c4 = (ch & 7) * 4;
      pa[j] = *reinterpret_cast<const float4*>(afb + (size_t)row * ldAf + kf + c4);
    }
  };
  if constexpr (FPA) {
    if (K1 == 0) loadA(0);  // K1>0 cases prefetch at iter K1-32
  }

  f32x4 acc[4][4] = {};

  for (int k0 = 0; k0 < K; k0 += 32) {
    __syncthreads();  // previous iter's LDS reads done
    if (!FPA || k0 < K1) {
#pragma unroll
      for (int j = 0; j < 2; ++j) {
        int ch = tid + j * 256, row = ch >> 2, c8 = ch & 3;
        const unsigned short* ga = A1 + (size_t)(m0 + row) * ldA1 + k0 + c8 * 8;
        __builtin_amdgcn_global_load_lds(
            (const __attribute__((address_space(1))) void*)ga,
            (__attribute__((address_space(3))) void*)(sA + ch * 8), 16, 0, 0);
      }
    } else {
      // consume prefetched fp32 tile: convert + stage
#pragma unroll
      for (int j = 0; j < 4; ++j) {
        int ch = tid + j * 256, row = ch >> 3, c4 = (ch & 7) * 4;
        ushort4 o;
        o.x = f2bf(pa[j].x); o.y = f2bf(pa[j].y);
        o.z = f2bf(pa[j].z); o.w = f2bf(pa[j].w);
        *reinterpret_cast<ushort4*>(sA + row * 32 + c4) = o;
      }
    }
#pragma unroll
    for (int j = 0; j < 2; ++j) {
      int ch = tid + j * 256, row = ch >> 2, c8 = ch & 3;
      const unsigned short* gb = Bbase + (size_t)(n0 + row) * K + k0 + c8 * 8;
      __builtin_amdgcn_global_load_lds(
          (const __attribute__((address_space(1))) void*)gb,
          (__attribute__((address_space(3))) void*)(sB + ch * 8), 16, 0, 0);
    }
    __syncthreads();  // staging visible (compiler drains vmcnt before barrier)

    // prefetch next fp32 A tile into regs — latency hides behind MFMA phase
    if constexpr (FPA) {
      int kn = k0 + 32;
      if (kn >= K1 && kn < K) loadA(kn);
    }

    bf16x8 af[4], bfr[4];
#pragma unroll
    for (int i = 0; i < 4; ++i)
      af[i] = *reinterpret_cast<const bf16x8*>(sA + (wm * 64 + i * 16 + r16) * 32 + quad * 8);
#pragma unroll
    for (int j = 0; j < 4; ++j)
      bfr[j] = *reinterpret_cast<const bf16x8*>(sB + (wn * 64 + j * 16 + r16) * 32 + quad * 8);
#pragma unroll
    for (int i = 0; i < 4; ++i)
#pragma unroll
      for (int j = 0; j < 4; ++j)
        acc[i][j] = __builtin_amdgcn_mfma_f32_16x16x32_bf16(af[i], bfr[j], acc[i][j], 0, 0, 0);
  }

  float ef = 0.0f;
  if (MODE == 2) ef = expf(factor[0]);

#pragma unroll
  for (int i = 0; i < 4; ++i) {
    int mbase = m0 + wm * 64 + i * 16 + quad * 4;
#pragma unroll
    for (int reg = 0; reg < 4; ++reg) {
      int m = mbase + reg;
      // MODE 2: hoist the dependent gather chain (gts/gto -> rowidx) per m.
      const float* so_row = nullptr;
      if (MODE == 2) {
        long rowidx = (long)gts[m] * OBJ_NUM + gto[m];
        so_row = so2p + rowidx * PRED_NUM;
      }
#pragma unroll
      for (int j = 0; j < 4; ++j) {
        int n = n0 + wn * 64 + j * 16 + r16;
        if (n < Nreal) {
          float v = acc[i][j][reg];
          if (MODE == 0) {
            v = fmaxf(v + bias_p[n], 0.0f);
            outB[(size_t)m * ldout + n] = f2bf(v);
          } else if (MODE == 1) {
            outF[(size_t)m * ldout + n] = v;
          } else {
            v += so_row[n] * ef;
            outF[(size_t)m * ldout + n] = v;
          }
        }
      }
    }
  }
}

// ---------------- launch ----------------

extern "C" void kernel_launch(void* const* d_in, const int* in_sizes, int n_in,
                              void* d_out, int out_size, void* d_ws, size_t ws_size,
                              hipStream_t stream) {
  const float* inp_sf  = (const float*)d_in[0];
  const float* inp_of  = (const float*)d_in[1];
  const float* inp_ppf = (const float*)d_in[2];
  const float* inp_pvf = (const float*)d_in[3];
  const int*   gt_s    = (const int*)d_in[4];
  const int*   gt_o    = (const int*)d_in[5];
  const float* W_obj1  = (const float*)d_in[6];
  const float* b_obj1  = (const float*)d_in[7];
  const float* W_obj2  = (const float*)d_in[8];
  const float* W_pvf   = (const float*)d_in[9];
  const float* b_pvf   = (const float*)d_in[10];
  const float* W_pf    = (const float*)d_in[11];
  const float* b_pf    = (const float*)d_in[12];
  const float* W_pred  = (const float*)d_in[13];
  const float* so2p    = (const float*)d_in[14];
  const float* so2p_f  = (const float*)d_in[15];

  float* out_s = (float*)d_out;                         // [16384,1001] (+ out_o right after)
  float* out_p = out_s + 2 * (size_t)BROWS * OBJ_NUM;   // [16384,132]

  char* ws = (char*)d_ws;
  unsigned short* H_buf = (unsigned short*)ws; ws += (size_t)3 * BROWS * HIDDEN * 2;  // 48 MB: s|o|pvf hidden
  unsigned short* H2    = (unsigned short*)ws; ws += (size_t)BROWS * HIDDEN * 2;      // 16 MB
  unsigned short* Wt_obj1 = (unsigned short*)ws; ws += (size_t)HIDDEN * OBJ_FEAT * 2;
  unsigned short* Wt_obj2 = (unsigned short*)ws; ws += (size_t)OBJ_PAD * HIDDEN * 2;
  unsigned short* Wt_pvf  = (unsigned short*)ws; ws += (size_t)HIDDEN * OBJ_FEAT * 2;
  unsigned short* Wt_pf   = (unsigned short*)ws; ws += (size_t)HIDDEN * PF_K * 2;
  unsigned short* Wt_pred = (unsigned short*)ws; ws += (size_t)PRED_PAD * HIDDEN * 2;

  // 1) weight casts
  cast_w_all<<<dim3(4, 1024, 5), 256, 0, stream>>>(
      W_obj1, W_obj2, W_pvf, W_pf, W_pred,
      Wt_obj1, Wt_obj2, Wt_pvf, Wt_pf, Wt_pred);

  // 2) merged hidden layer: rows [0,16384)=sf, [16384,32768)=of  x W_obj1+b_obj1;
  //    rows [32768,49152)=pvf x W_pvf + b_pvf  -> H_buf bf16 relu.
  //    A is fp32 direct (reg-staged convert path).
  gemm_fused<0, 1><<<dim3(HIDDEN / 128, 3 * BROWS / 128), 256, 0, stream>>>(
      nullptr, 0, 0,
      inp_sf, inp_of, inp_pvf, BROWS, OBJ_FEAT,
      Wt_obj1, OBJ_FEAT,
      2 * BROWS, Wt_pvf, b_pvf,
      nullptr, H_buf, HIDDEN, HIDDEN, b_obj1,
      nullptr, nullptr, nullptr, nullptr);

  // 3) s+o scores: [32768,512] bf16 x W_obj2 -> out_s|out_o fp32
  gemm_fused<1, 0><<<dim3(OBJ_PAD / 128, 2 * BROWS / 128), 256, 0, stream>>>(
      H_buf, HIDDEN, HIDDEN,
      nullptr, nullptr, nullptr, 0, 0,
      Wt_obj2, HIDDEN,
      1 << 30, nullptr, nullptr,
      out_s, nullptr, OBJ_NUM, OBJ_NUM, nullptr,
      nullptr, nullptr, nullptr, nullptr);

  // 4) pf_emb: A = [pvf_emb bf16 (k<512) | ppf fp32 (k>=512)] x W_pf -> H2 relu
  gemm_fused<0, 1><<<dim3(HIDDEN / 128, BROWS / 128), 256, 0, stream>>>(
      H_buf + (size_t)2 * BROWS * HIDDEN, HIDDEN, HIDDEN,
      inp_ppf, nullptr, nullptr, 1 << 30, PPF_DIM,
      Wt_pf, PF_K,
      1 << 30, nullptr, nullptr,
      nullptr, H2, HIDDEN, HIDDEN, b_pf,
      nullptr, nullptr, nullptr, nullptr);

  // 5) p_score + knowledge gather
  gemm_fused<2, 0><<<dim3(PRED_PAD / 128, BROWS / 128), 256, 0, stream>>>(
      H2, HIDDEN, HIDDEN,
      nullptr, nullptr, nullptr, 0, 0,
      Wt_pred, HIDDEN,
      1 << 30, nullptr, nullptr,
      out_p, nullptr, PRED_NUM, PRED_NUM, nullptr,
      gt_s, gt_o, so2p, so2p_f);

  (void)in_sizes; (void)n_in; (void)out_size; (void)ws_size;
}